// Round 15
// baseline (718.014 us; speedup 1.0000x reference)
//
#include <hip/hip_runtime.h>
#include <hip/hip_bf16.h>

// ---------------------------------------------------------------------------
// CrossGatingBlock on MI355X (gfx950).  Round 15.
// Isolated change vs r13: mlp3c LDS 64KB -> 32KB via chunking (stage A/B
// loop over two g-halves; Ts2/stage C loop over two d-halves) +
// launch_bounds(512,4).  Guarantees >=2 blocks/CU residency, which the
// r13 64KB experiment failed to achieve (occ stuck at 22% = 1 block/CU).
// ---------------------------------------------------------------------------

typedef unsigned short u16;
typedef __bf16 bf16x8 __attribute__((ext_vector_type(8)));
typedef u16    u16x8  __attribute__((ext_vector_type(8)));
typedef u16    u16x4  __attribute__((ext_vector_type(4)));
typedef float  f32x4  __attribute__((ext_vector_type(4)));

__device__ __forceinline__ float bf2f(u16 u) {
  union { float f; unsigned int i; } v; v.i = ((unsigned int)u) << 16; return v.f;
}
__device__ __forceinline__ u16 f2bf(float f) {   // RNE
  union { float f; unsigned int i; } v; v.f = f;
  unsigned int x = v.i;
  return (u16)((x + 0x7fffu + ((x >> 16) & 1u)) >> 16);
}
__device__ __forceinline__ f32x4 mfma16(u16x8 a, u16x8 b, f32x4 c) {
  return __builtin_amdgcn_mfma_f32_16x16x32_bf16(
      __builtin_bit_cast(bf16x8, a), __builtin_bit_cast(bf16x8, b), c, 0, 0, 0);
}
// fast gelu (r12): v * sigmoid(1.5958*v*(1+0.044715*v^2)) via 2^z + rcp.
__device__ __forceinline__ float gelu_erf(float v) {
  const float z = v * (-2.3022586f - 0.10294276f * v * v);
  return __fdividef(v, 1.f + exp2f(z));
}

// ---------------------------------------------------------------------------
// prep_k: all weight transposes + 4 LN colsums + stats zeroing.  (r11)
// ---------------------------------------------------------------------------
__global__ __launch_bounds__(256) void prep_k(
    const float* __restrict__ wc1f, const float* __restrict__ wc2f,
    const float* __restrict__ wl1f, const float* __restrict__ wl2f,
    const float* __restrict__ wl3f, const float* __restrict__ wl4f,
    const float* __restrict__ g1w1, const float* __restrict__ g2w1,
    const float* __restrict__ g1w4, const float* __restrict__ g2w4,
    const float* __restrict__ g1w2, const float* __restrict__ g2w2,
    const float* __restrict__ g1w3, const float* __restrict__ g2w3,
    const float* __restrict__ wtf,
    u16* __restrict__ wb, float* __restrict__ cs, float* __restrict__ ps) {
  const int b = blockIdx.x, t = threadIdx.x;
  if (b < 384) {                       // 6x [128][128]
    const float* src = b < 64 ? wc1f : b < 128 ? wc2f : b < 192 ? wl1f
                     : b < 256 ? wl2f : b < 320 ? wl3f : wl4f;
    const int w = b >> 6;
    const int i = ((b & 63) << 8) + t;           // < 16384
    const int d = i >> 7, c = i & 127;
    wb[w * 16384 + i] = f2bf(src[c * 128 + d]);
  } else if (b < 640) {                // g1w1/g2w1 [128][256] -> [256][128]
    const float* src = b < 512 ? g1w1 : g2w1;
    const int base = b < 512 ? 98304 : 131072;
    const int i = (((b - (b < 512 ? 384 : 512)) << 8) + t);  // < 32768
    const int d = i >> 7, c = i & 127;
    wb[base + i] = f2bf(src[c * 256 + d]);
  } else if (b < 896) {                // g1w4/g2w4 [256][128] -> [128][256]
    const float* src = b < 768 ? g1w4 : g2w4;
    const int base = b < 768 ? 163840 : 196608;
    const int i = (((b - (b < 768 ? 640 : 768)) << 8) + t);  // < 32768
    const int d = i >> 8, c = i & 255;
    wb[base + i] = f2bf(src[c * 128 + d]);
  } else if (b < 1920) {               // 4x [256][256] transpose
    const int w = (b - 896) >> 8;                 // 0..3
    const float* src = w == 0 ? g1w2 : w == 1 ? g2w2 : w == 2 ? g1w3 : g2w3;
    const int base = 229376 + w * 65536;
    const int i = (((b - 896) & 255) << 8) + t;   // < 65536
    const int d = i >> 8, g = i & 255;
    wb[base + i] = f2bf(src[g * 256 + d]);
  } else if (b < 2432) {               // wtb[kl*128+o][c] from wt(c,o,kh,kw)
    const int i = ((b - 1920) << 8) + t;          // < 131072
    const int c = i & 255, r = i >> 8, o = r & 127, kl = r >> 7;
    wb[491520 + i] = f2bf(wtf[(c * 128 + o) * 4 + kl]);
  } else if (b < 2436) {               // colsums (bf16-rounded)
    const int w = b - 2432;
    const float* src = w == 0 ? wl1f : w == 1 ? wl2f : w == 2 ? g1w1 : g2w1;
    const int cout = w < 2 ? 128 : 256;
    if (t < cout) {
      float s = 0.f;
      for (int c = 0; c < 128; ++c) s += bf2f(f2bf(src[c * cout + t]));
      cs[w * 256 + t] = s;
    }
  } else {                             // zero stats slots
    if (t < 64) ps[t] = 0.f;
  }
}

// ---------------------------------------------------------------------------
// gemmYX_k: MERGED first-stage kernel.  (r11)
// ---------------------------------------------------------------------------
__global__ __launch_bounds__(256, 2) void gemmYX_k(
    const float* __restrict__ Y, const float* __restrict__ X,
    const u16* __restrict__ Wtb, const float* __restrict__ bt,
    const u16* __restrict__ Wc2, const float* __restrict__ bc2,
    const u16* __restrict__ Wc1, const float* __restrict__ bc1,
    u16* __restrict__ oy, u16* __restrict__ ox, float* __restrict__ ps) {
  __shared__ u16 sm[25088];       // Y2: As 16384 + Cs 8704 | X: As 17408
  __shared__ float red[8];
  const int tid = threadIdx.x;
  const int wid = tid >> 6, lane = tid & 63, fr = lane & 15, fg = lane >> 4;

  if (blockIdx.x < 512) {
    // ---------------- Y path (ConvT + conv1x1 fused) ----------------
    u16* As = sm;                 // [64 tok][256 c] swizzled
    u16* Cs = sm + 16384;         // [64 tok][136]
    float* pso = ps + 16;
    const int m0 = blockIdx.x * 64;
    const int ns = m0 >> 12, pb = m0 & 4095;
    const int tokg = (wid & 1) * 32;
    const int chg  = (wid >> 1) * 64;
    const int xorl = (fr & 7) << 4;

#pragma unroll
    for (int it = 0; it < 16; ++it) {
      const int idx = it * 256 + tid;          // < 4096
      const int c = idx & 255, t4 = idx >> 8;  // t4 0..15
      const f32x4 v = *(const f32x4*)(Y + (((size_t)(ns * 256 + c)) << 12) + pb + t4 * 4);
#pragma unroll
      for (int r = 0; r < 4; ++r) {
        const int tok = t4 * 4 + r;
        const int byte = (tok * 512 + c * 2) ^ ((tok & 7) << 4);
        *(u16*)((char*)As + byte) = f2bf(v[r]);
      }
    }
    __syncthreads();

    float s1 = 0.f, s2 = 0.f;
    for (int kl = 0; kl < 4; ++kl) {
      if (kl) __syncthreads();
      f32x4 acc1[2][4] = {};
      {
        const u16* Brow = Wtb + (size_t)(kl * 128 + chg + fr) * 256;
#pragma unroll
        for (int ks = 0; ks < 8; ++ks) {
          const int kb = ks * 32 + fg * 8;
          u16x8 a_[2], b_[4];
#pragma unroll
          for (int i = 0; i < 2; ++i) {
            const int tok = tokg + i * 16 + fr;
            const int byte = (tok * 512 + kb * 2) ^ xorl;
            a_[i] = *(const u16x8*)((const char*)As + byte);
          }
#pragma unroll
          for (int j = 0; j < 4; ++j)
            b_[j] = *(const u16x8*)(Brow + (size_t)j * 16 * 256 + kb);
#pragma unroll
          for (int i = 0; i < 2; ++i)
#pragma unroll
            for (int j = 0; j < 4; ++j) acc1[i][j] = mfma16(b_[j], a_[i], acc1[i][j]);
        }
      }
#pragma unroll
      for (int i = 0; i < 2; ++i) {
        const int tok = tokg + i * 16 + fr;
#pragma unroll
        for (int j = 0; j < 4; ++j) {
          const int o0 = chg + j * 16 + fg * 4;
          const f32x4 bz = *(const f32x4*)(bt + o0);
          u16x4 sv;
#pragma unroll
          for (int r = 0; r < 4; ++r) sv[r] = f2bf(fmaxf(acc1[i][j][r] + bz[r], 0.f));
          *(u16x4*)(Cs + tok * 136 + o0) = sv;
        }
      }
      __syncthreads();
      f32x4 acc2[2][4] = {};
      {
        const u16* Brow = Wc2 + (size_t)(chg + fr) * 128;
#pragma unroll
        for (int ks = 0; ks < 4; ++ks) {
          const int kb = ks * 32 + fg * 8;
          u16x8 a_[2], b_[4];
#pragma unroll
          for (int i = 0; i < 2; ++i)
            a_[i] = *(const u16x8*)(Cs + (tokg + i * 16 + fr) * 136 + kb);
#pragma unroll
          for (int j = 0; j < 4; ++j)
            b_[j] = *(const u16x8*)(Brow + (size_t)j * 16 * 128 + kb);
#pragma unroll
          for (int i = 0; i < 2; ++i)
#pragma unroll
            for (int j = 0; j < 4; ++j) acc2[i][j] = mfma16(b_[j], a_[i], acc2[i][j]);
        }
      }
#pragma unroll
      for (int i = 0; i < 2; ++i) {
        const int ytok = m0 + tokg + i * 16 + fr;
        const int hy = (ytok >> 6) & 63, wy = ytok & 63;
        const int opix = ((ns * 128 + 2 * hy + (kl >> 1)) << 7) + 2 * wy + (kl & 1);
#pragma unroll
        for (int j = 0; j < 4; ++j) {
          const int ch0 = chg + j * 16 + fg * 4;
          const f32x4 bz = *(const f32x4*)(bc2 + ch0);
          u16x4 sv;
#pragma unroll
          for (int r = 0; r < 4; ++r) {
            float v = fmaxf(acc2[i][j][r] + bz[r], 0.f);
            s1 += v; s2 += v * v;
            sv[r] = f2bf(v);
          }
          *(u16x4*)(oy + (size_t)opix * 128 + ch0) = sv;
        }
      }
    }
#pragma unroll
    for (int off = 32; off > 0; off >>= 1) {
      s1 += __shfl_down(s1, off); s2 += __shfl_down(s2, off);
    }
    if (lane == 0) { red[wid] = s1; red[4 + wid] = s2; }
    __syncthreads();
    if (tid == 0)  atomicAdd(&pso[2 * ns],     red[0] + red[1] + red[2] + red[3]);
    if (tid == 64) atomicAdd(&pso[2 * ns + 1], red[4] + red[5] + red[6] + red[7]);
  } else {
    // ---------------- X path (conv1x1 from fp32 NCHW) ----------------
    u16* As = sm;                 // [128 tok][136]
    float* pso = ps;
    const int m0 = (blockIdx.x - 512) * 128;
    const int ns = m0 >> 14, pb = m0 & 16383;
    const int wmt = (wid & 1) * 64, wnc = (wid >> 1) * 64;

#pragma unroll
    for (int it = 0; it < 16; ++it) {
      const int idx = it * 256 + tid;          // < 4096
      const int c = idx & 127, t4 = idx >> 7;  // t4 0..31
      const f32x4 v = *(const f32x4*)(X + (((size_t)(ns * 128 + c)) << 14) + pb + t4 * 4);
#pragma unroll
      for (int r = 0; r < 4; ++r) As[(t4 * 4 + r) * 136 + c] = f2bf(v[r]);
    }
    __syncthreads();

    f32x4 acc[4][4] = {};
    const u16* Brow = Wc1 + (size_t)(wnc + fr) * 128;
    u16x8 a[4][4];
#pragma unroll
    for (int ks = 0; ks < 4; ++ks) {
      const int kb = ks * 32 + fg * 8;
#pragma unroll
      for (int i = 0; i < 4; ++i)
        a[ks][i] = *(const u16x8*)(As + (wmt + i * 16 + fr) * 136 + kb);
    }
#pragma unroll
    for (int ks = 0; ks < 4; ++ks) {
      const int kb = ks * 32 + fg * 8;
      u16x8 b_[4];
#pragma unroll
      for (int j = 0; j < 4; ++j)
        b_[j] = *(const u16x8*)(Brow + (size_t)j * 16 * 128 + kb);
#pragma unroll
      for (int i = 0; i < 4; ++i)
#pragma unroll
        for (int j = 0; j < 4; ++j) acc[i][j] = mfma16(b_[j], a[ks][i], acc[i][j]);
    }

    float s1 = 0.f, s2 = 0.f;
#pragma unroll
    for (int i = 0; i < 4; ++i) {
      const int token = m0 + wmt + i * 16 + fr;
#pragma unroll
      for (int j = 0; j < 4; ++j) {
        const int ch0 = wnc + j * 16 + fg * 4;
        const f32x4 bz = *(const f32x4*)(bc1 + ch0);
        f32x4 v = acc[i][j];
        u16x4 sv;
#pragma unroll
        for (int r = 0; r < 4; ++r) {
          v[r] = fmaxf(v[r] + bz[r], 0.f);
          s1 += v[r]; s2 += v[r] * v[r];
          sv[r] = f2bf(v[r]);
        }
        *(u16x4*)(ox + (size_t)token * 128 + ch0) = sv;
      }
    }
#pragma unroll
    for (int off = 32; off > 0; off >>= 1) {
      s1 += __shfl_down(s1, off); s2 += __shfl_down(s2, off);
    }
    if (lane == 0) { red[wid] = s1; red[4 + wid] = s2; }
    __syncthreads();
    if (tid == 0)  atomicAdd(&pso[2 * ns],     red[0] + red[1] + red[2] + red[3]);
    if (tid == 64) atomicAdd(&pso[2 * ns + 1], red[4] + red[5] + red[6] + red[7]);
  }
}

// ---------------------------------------------------------------------------
// gemm4d_k: DUAL-BRANCH barrier-free CIN=128 GEMM.  (r11)
// ---------------------------------------------------------------------------
__global__ __launch_bounds__(256, 2) void gemm4d_k(
    const u16* __restrict__ Ay, const u16* __restrict__ Ax,
    const u16* __restrict__ Wty, const u16* __restrict__ Wtx,
    const float* __restrict__ by, const float* __restrict__ bx,
    float* __restrict__ ps,            // [ps0 x0|ps1 y0|ps2 x1|ps3 y1] x16
    const float* __restrict__ csy, const float* __restrict__ csx,
    u16* __restrict__ oy, u16* __restrict__ ox) {
  __shared__ float red[8];
  const int br = blockIdx.y;
  const u16* A1 = br ? Ax : Ay;
  const u16* Wt = br ? Wtx : Wty;
  const float* bias = br ? bx : by;
  const float* pst = ps + (br ? 0 : 16);
  float* pso = ps + (br ? 32 : 48);
  const float* cs = br ? csx : csy;
  u16* out = br ? ox : oy;

  const int tid = threadIdx.x;
  const int m0 = blockIdx.x * 128;
  const int wid = tid >> 6, lane = tid & 63, fr = lane & 15, fg = lane >> 4;
  const int wmt = (wid & 1) * 64, wnc = (wid >> 1) * 64;

  f32x4 acc[4][4] = {};
  const u16* Arow = A1 + (size_t)(m0 + wmt + fr) * 128;
  const u16* Brow = Wt + (size_t)(wnc + fr) * 128;

  u16x8 a[4][4];
#pragma unroll
  for (int ks = 0; ks < 4; ++ks) {
    const int kb = ks * 32 + fg * 8;
#pragma unroll
    for (int i = 0; i < 4; ++i)
      a[ks][i] = *(const u16x8*)(Arow + (size_t)i * 16 * 128 + kb);
  }
#pragma unroll
  for (int ks = 0; ks < 4; ++ks) {
    const int kb = ks * 32 + fg * 8;
    u16x8 b_[4];
#pragma unroll
    for (int j = 0; j < 4; ++j)
      b_[j] = *(const u16x8*)(Brow + (size_t)j * 16 * 128 + kb);
#pragma unroll
    for (int i = 0; i < 4; ++i)
#pragma unroll
      for (int j = 0; j < 4; ++j) acc[i][j] = mfma16(b_[j], a[ks][i], acc[i][j]);
  }

  const int s = m0 >> 14;
  const float inv_n = 1.f / 2097152.f;
  const float mean = pst[2 * s] * inv_n;
  const float var = pst[2 * s + 1] * inv_n - mean * mean;
  const float alpha = rsqrtf(var + 1e-5f);
  const float beta = -mean * alpha;

  float s1 = 0.f, s2 = 0.f;
#pragma unroll
  for (int i = 0; i < 4; ++i) {
    const int token = m0 + wmt + i * 16 + fr;
#pragma unroll
    for (int j = 0; j < 4; ++j) {
      const int ch0 = wnc + j * 16 + fg * 4;
      const f32x4 bz = *(const f32x4*)(bias + ch0);
      const f32x4 csv = *(const f32x4*)(cs + ch0);
      f32x4 v = acc[i][j];
      u16x4 sv;
#pragma unroll
      for (int r = 0; r < 4; ++r) {
        v[r] = v[r] * alpha + beta * csv[r] + bz[r];
        v[r] = gelu_erf(v[r]);
        s1 += v[r]; s2 += v[r] * v[r];
        sv[r] = f2bf(v[r]);
      }
      *(u16x4*)(out + (size_t)token * 128 + ch0) = sv;
    }
  }
#pragma unroll
  for (int off = 32; off > 0; off >>= 1) {
    s1 += __shfl_down(s1, off); s2 += __shfl_down(s2, off);
  }
  if (lane == 0) { red[wid] = s1; red[4 + wid] = s2; }
  __syncthreads();
  if (tid == 0)  atomicAdd(&pso[2 * s],     red[0] + red[1] + red[2] + red[3]);
  if (tid == 64) atomicAdd(&pso[2 * s + 1], red[4] + red[5] + red[6] + red[7]);
}

// ---------------------------------------------------------------------------
// mlp3c_k: DUAL-BRANCH fused gating chain, 32KB LDS (chunked).
//   stages A+B: loop gi over two g-halves: stage A writes t[c][g_half] to
//   32KB Ts; stage B accumulates accB over that K-half.
//   stages Ts2+C: loop di over two d-halves: half the waves write m[d_half][c]
//   to Ts; stage C computes gpart for pix(d_half).
// MODE 0 writes g partial (+b4).  MODE 1 adds partial and multiplies by the
// OTHER branch's activation -> finished product y1*gx / x1*gy.
// ---------------------------------------------------------------------------
template <int MODE>
__global__ __launch_bounds__(512, 4) void mlp3c_k(
    const u16* __restrict__ a1y, const u16* __restrict__ a1x,
    const u16* __restrict__ w1y, const u16* __restrict__ w1x,
    const float* __restrict__ b1y, const float* __restrict__ b1x,
    const float* __restrict__ ps,
    const float* __restrict__ csy, const float* __restrict__ csx,
    const u16* __restrict__ w2y, const u16* __restrict__ w2x,
    const float* __restrict__ b2y, const float* __restrict__ b2x,
    const u16* __restrict__ w4y, const u16* __restrict__ w4x,
    const float* __restrict__ b4y, const float* __restrict__ b4x,
    u16* __restrict__ goy, u16* __restrict__ gox) {
  __shared__ u16 Ts[16384];     // 32KB -> >=2 blocks/CU
  const int br = blockIdx.z;
  const u16* y1 = br ? a1x : a1y;
  const u16* mulp = br ? a1y : a1x;          // other branch's activation
  const u16* w1b = br ? w1x : w1y;
  const float* b1 = br ? b1x : b1y;
  const float* pst = ps + (br ? 32 : 48);
  const float* csb = br ? csx : csy;
  const u16* w2b = br ? w2x : w2y;
  const float* b2 = br ? b2x : b2y;
  const u16* w4b = br ? w4x : w4y;
  const float* b4 = br ? b4x : b4y;
  u16* gout = br ? gox : goy;

  const int q2 = blockIdx.x, ns = blockIdx.y;
  const int tid = threadIdx.x;
  constexpr int coff = MODE ? 128 : 0;
  const int wid = tid >> 6, lane = tid & 63, fr = lane & 15, fg = lane >> 4;
  const int xorl = (fr & 7) << 4;

  int pbase, prow, pcol;
  if constexpr (MODE == 0) {    // q=(gh*16+gw), fixed p2=(ph*8+pw)
    pbase = ns * 16384 + (q2 >> 3) * 128 + (q2 & 7);
    prow = 1024; pcol = 8;
  } else {                      // block cell fixed, q=(ph*16+pw)
    pbase = ns * 16384 + (q2 >> 3) * 2048 + (q2 & 7) * 16;
    prow = 128; pcol = 1;
  }
  auto pix = [&](int q) { return pbase + (q >> 4) * prow + (q & 15) * pcol; };

  // ---------------- stages A+B over two g-halves ----------------
  f32x4 accB[4][4] = {};               // [i: c-sub][j: d-sub]
  const int wcs = (wid >> 2) * 64;     // c: 2 groups x 64
  const int wds = (wid & 3) * 64;      // d: 4 groups x 64
  {
    const float inv_n = 1.f / 2097152.f;
    const float mean = pst[2 * ns] * inv_n;
    const float var = pst[2 * ns + 1] * inv_n - mean * mean;
    const float alpha = rsqrtf(var + 1e-5f);
    const float beta = -mean * alpha;
    const int wgt = (wid >> 1) * 32;   // g_local: 4 groups x 32
    const int wc  = (wid & 1) * 64;    // c: 2 groups x 64

#pragma unroll
    for (int gi = 0; gi < 2; ++gi) {
      if (gi) __syncthreads();         // stage-B reads of prev chunk done
      // ---- stage A chunk: t[c][g_local] for g in [gi*128, gi*128+128)
      {
        f32x4 acc[2][4] = {};
        const u16* ar[2];
#pragma unroll
        for (int i = 0; i < 2; ++i)
          ar[i] = y1 + (size_t)pix(gi * 128 + wgt + i * 16 + fr) * 128;
        const u16* br_ = w1b + (size_t)(coff + wc + fr) * 128;
        u16x8 a[4][2];
#pragma unroll
        for (int ks = 0; ks < 4; ++ks) {
          const int kb = ks * 32 + fg * 8;
#pragma unroll
          for (int i = 0; i < 2; ++i) a[ks][i] = *(const u16x8*)(ar[i] + kb);
        }
#pragma unroll
        for (int ks = 0; ks < 4; ++ks) {
          const int kb = ks * 32 + fg * 8;
          u16x8 b_[4];
#pragma unroll
          for (int j = 0; j < 4; ++j)
            b_[j] = *(const u16x8*)(br_ + (size_t)j * 16 * 128 + kb);
#pragma unroll
          for (int i = 0; i < 2; ++i)
#pragma unroll
            for (int j = 0; j < 4; ++j) acc[i][j] = mfma16(a[ks][i], b_[j], acc[i][j]);
        }
#pragma unroll
        for (int j = 0; j < 4; ++j) {
          const int c = wc + j * 16 + fr;
          const float cv = csb[coff + c];
          const float bz = b1[coff + c];
#pragma unroll
          for (int i = 0; i < 2; ++i) {
            const int g0 = wgt + i * 16 + fg * 4;      // local g
            u16x4 sv;
#pragma unroll
            for (int r = 0; r < 4; ++r)
              sv[r] = f2bf(gelu_erf(acc[i][j][r] * alpha + beta * cv + bz));
            const int byte = (c * 256 + g0 * 2) ^ xorl;
            *(u16x4*)((char*)Ts + byte) = sv;
          }
        }
      }
      __syncthreads();
      // ---- stage B chunk: accB += t[c][k] * w2[gi*128+k][d]
      {
        const u16* br_ = w2b + (size_t)(wds + fr) * 256 + gi * 128;
#pragma unroll
        for (int ks = 0; ks < 4; ++ks) {
          const int kb = ks * 32 + fg * 8;
          u16x8 a_[4], b_[4];
#pragma unroll
          for (int i = 0; i < 4; ++i) {
            const int c = wcs + i * 16 + fr;
            const int byte = (c * 256 + kb * 2) ^ xorl;
            a_[i] = *(const u16x8*)((const char*)Ts + byte);
          }
#pragma unroll
          for (int j = 0; j < 4; ++j)
            b_[j] = *(const u16x8*)(br_ + (size_t)j * 16 * 256 + kb);
#pragma unroll
          for (int i = 0; i < 4; ++i)
#pragma unroll
            for (int j = 0; j < 4; ++j) accB[i][j] = mfma16(a_[i], b_[j], accB[i][j]);
        }
      }
    }
  }

  // ---------------- stages Ts2+C over two d-halves ----------------
#pragma unroll
  for (int di = 0; di < 2; ++di) {
    __syncthreads();               // prev Ts reads (B or C) done
    // write m[d][c] for d in chunk (waves with (wid>>1)&1 == di)
    if (((wid >> 1) & 1) == di) {
#pragma unroll
      for (int j = 0; j < 4; ++j) {
        const int d = wds + j * 16 + fr;
        const int dl = d - di * 128;
        const float bz = b2[d];
        const int dx = (dl & 7) << 4;
#pragma unroll
        for (int i = 0; i < 4; ++i) {
          const int c0 = wcs + i * 16 + fg * 4;
          u16x4 sv;
#pragma unroll
          for (int r = 0; r < 4; ++r) sv[r] = f2bf(accB[i][j][r] + bz);
          const int byte = (dl * 256 + c0 * 2) ^ dx;
          *(u16x4*)((char*)Ts + byte) = sv;
        }
      }
    }
    __syncthreads();
    // stage C chunk: gpart for pix(d), d in [di*128, di*128+128)
    {
      const int wp = (wid >> 1) * 32;  // d_local: 4 groups x 32
      const int wo = (wid & 1) * 64;   // o: 2 groups x 64
      f32x4 accC[2][4] = {};           // [i: pix][j: o]
      const u16* br_ = w4b + (size_t)(wo + fr) * 256 + coff;
#pragma unroll
      for (int ks = 0; ks < 4; ++ks) {
        const int kb = ks * 32 + fg * 8;
        u16x8 a_[2], b_[4];
#pragma unroll
        for (int i = 0; i < 2; ++i) {
          const int dl = wp + i * 16 + fr;
          const int byte = (dl * 256 + kb * 2) ^ ((dl & 7) << 4);
          a_[i] = *(const u16x8*)((const char*)Ts + byte);
        }
#pragma unroll
        for (int j = 0; j < 4; ++j)
          b_[j] = *(const u16x8*)(br_ + (size_t)j * 16 * 256 + kb);
#pragma unroll
        for (int i = 0; i < 2; ++i)
#pragma unroll
          for (int j = 0; j < 4; ++j) accC[i][j] = mfma16(b_[j], a_[i], accC[i][j]);
      }
#pragma unroll
      for (int i = 0; i < 2; ++i) {
        const size_t pg = (size_t)pix(di * 128 + wp + i * 16 + fr) * 128;
#pragma unroll
        for (int j = 0; j < 4; ++j) {
          const int o0 = wo + j * 16 + fg * 4;
          f32x4 v = accC[i][j];
          u16x4 sv;
          if constexpr (MODE == 0) {
            const f32x4 bz = *(const f32x4*)(b4 + o0);
#pragma unroll
            for (int r = 0; r < 4; ++r) sv[r] = f2bf(v[r] + bz[r]);
          } else {
            const u16x4 pv = *(const u16x4*)(gout + pg + o0);
            const u16x4 mv = *(const u16x4*)(mulp + pg + o0);
#pragma unroll
            for (int r = 0; r < 4; ++r)
              sv[r] = f2bf((v[r] + bf2f(pv[r])) * bf2f(mv[r]));
          }
          *(u16x4*)(gout + pg + o0) = sv;
        }
      }
    }
  }
}

// ---------------------------------------------------------------------------
// dual5_k: LDS-free, barrier-free finale.  (r11)
// ---------------------------------------------------------------------------
__global__ __launch_bounds__(256, 2) void dual5_k(
    const u16* __restrict__ y1g, const u16* __restrict__ x1g,
    const u16* __restrict__ w3b, const u16* __restrict__ w4b,
    const float* __restrict__ b3, const float* __restrict__ b4,
    const u16* __restrict__ y0, const u16* __restrict__ x0,
    float* __restrict__ outy, float* __restrict__ outx) {
  const int tid = threadIdx.x;
  const int m0 = blockIdx.x * 128;
  const int wid = tid >> 6, lane = tid & 63, fr = lane & 15, fg = lane >> 4;
  const int wmt = (wid & 1) * 64, wnc = (wid >> 1) * 64;

  f32x4 acc[4][4] = {};
  u16x4 y9[4][4];

  // ---- pass 1: acc = y1g @ w3
  {
    const u16* Arow = y1g + (size_t)(m0 + wmt + fr) * 128;
    const u16* Brow = w3b + (size_t)(wnc + fr) * 128;
    u16x8 a[4][4];
#pragma unroll
    for (int ks = 0; ks < 4; ++ks) {
      const int kb = ks * 32 + fg * 8;
#pragma unroll
      for (int i = 0; i < 4; ++i)
        a[ks][i] = *(const u16x8*)(Arow + (size_t)i * 16 * 128 + kb);
    }
#pragma unroll
    for (int ks = 0; ks < 4; ++ks) {
      const int kb = ks * 32 + fg * 8;
      u16x8 b_[4];
#pragma unroll
      for (int j = 0; j < 4; ++j) b_[j] = *(const u16x8*)(Brow + (size_t)j * 16 * 128 + kb);
#pragma unroll
      for (int i = 0; i < 4; ++i)
#pragma unroll
        for (int j = 0; j < 4; ++j) acc[i][j] = mfma16(b_[j], a[ks][i], acc[i][j]);
    }
  }
  // epilogue 1
  {
    u16x4 scv[4][4];
#pragma unroll
    for (int i = 0; i < 4; ++i) {
      const int token = m0 + wmt + i * 16 + fr;
#pragma unroll
      for (int j = 0; j < 4; ++j)
        scv[i][j] = *(const u16x4*)(y0 + (size_t)token * 128 + wnc + j * 16 + fg * 4);
    }
#pragma unroll
    for (int i = 0; i < 4; ++i) {
      const int token = m0 + wmt + i * 16 + fr;
      const int ns = token >> 14, p = token & 16383;
#pragma unroll
      for (int j = 0; j < 4; ++j) {
        const int ch0 = wnc + j * 16 + fg * 4;
        const f32x4 bz = *(const f32x4*)(b3 + ch0);
        f32x4 v = acc[i][j];
#pragma unroll
        for (int r = 0; r < 4; ++r) {
          v[r] += bz[r] + bf2f(scv[i][j][r]);
          outy[((size_t)(ns * 128 + ch0 + r) << 14) + p] = v[r];
          y9[i][j][r] = f2bf(v[r]);
        }
        acc[i][j] = f32x4{0.f, 0.f, 0.f, 0.f};
      }
    }
  }
  // ---- pass 2: acc = x1g @ w4
  {
    const u16* Arow = x1g + (size_t)(m0 + wmt + fr) * 128;
    const u16* Brow = w4b + (size_t)(wnc + fr) * 128;
    u16x8 a[4][4];
#pragma unroll
    for (int ks = 0; ks < 4; ++ks) {
      const int kb = ks * 32 + fg * 8;
#pragma unroll
      for (int i = 0; i < 4; ++i)
        a[ks][i] = *(const u16x8*)(Arow + (size_t)i * 16 * 128 + kb);
    }
#pragma unroll
    for (int ks = 0; ks < 4; ++ks) {
      const int kb = ks * 32 + fg * 8;
      u16x8 b_[4];
#pragma unroll
      for (int j = 0; j < 4; ++j) b_[j] = *(const u16x8*)(Brow + (size_t)j * 16 * 128 + kb);
#pragma unroll
      for (int i = 0; i < 4; ++i)
#pragma unroll
        for (int j = 0; j < 4; ++j) acc[i][j] = mfma16(b_[j], a[ks][i], acc[i][j]);
    }
  }
  // epilogue 2
  {
    u16x4 scv[4][4];
#pragma unroll
    for (int i = 0; i < 4; ++i) {
      const int token = m0 + wmt + i * 16 + fr;
#pragma unroll
      for (int j = 0; j < 4; ++j)
        scv[i][j] = *(const u16x4*)(x0 + (size_t)token * 128 + wnc + j * 16 + fg * 4);
    }
#pragma unroll
    for (int i = 0; i < 4; ++i) {
      const int token = m0 + wmt + i * 16 + fr;
      const int ns = token >> 14, p = token & 16383;
#pragma unroll
      for (int j = 0; j < 4; ++j) {
        const int ch0 = wnc + j * 16 + fg * 4;
        const f32x4 bz = *(const f32x4*)(b4 + ch0);
        f32x4 v = acc[i][j];
#pragma unroll
        for (int r = 0; r < 4; ++r) {
          v[r] += bz[r] + bf2f(y9[i][j][r]) + bf2f(scv[i][j][r]);
          outx[((size_t)(ns * 128 + ch0 + r) << 14) + p] = v[r];
        }
      }
    }
  }
}

// ---------------------------------------------------------------------------
extern "C" void kernel_launch(void* const* d_in, const int* in_sizes, int n_in,
                              void* d_out, int out_size, void* d_ws, size_t ws_size,
                              hipStream_t stream) {
  (void)in_sizes; (void)n_in; (void)out_size; (void)ws_size;
  const float* xf   = (const float*)d_in[0];
  const float* yf   = (const float*)d_in[1];
  const float* wtf  = (const float*)d_in[2];
  const float* btf  = (const float*)d_in[3];
  const float* wc1f = (const float*)d_in[4];
  const float* bc1f = (const float*)d_in[5];
  const float* wc2f = (const float*)d_in[6];
  const float* bc2f = (const float*)d_in[7];
  const float* wl1f = (const float*)d_in[8];
  const float* bl1f = (const float*)d_in[9];
  const float* wl2f = (const float*)d_in[10];
  const float* bl2f = (const float*)d_in[11];
  const float* wl3f = (const float*)d_in[12];
  const float* bl3f = (const float*)d_in[13];
  const float* wl4f = (const float*)d_in[14];
  const float* bl4f = (const float*)d_in[15];
  const float* g1w1 = (const float*)d_in[16];
  const float* g1b1 = (const float*)d_in[17];
  const float* g1w2 = (const float*)d_in[18];
  const float* g1b2 = (const float*)d_in[19];
  const float* g1w3 = (const float*)d_in[20];
  const float* g1b3 = (const float*)d_in[21];
  const float* g1w4 = (const float*)d_in[22];
  const float* g1b4 = (const float*)d_in[23];
  const float* g2w1 = (const float*)d_in[24];
  const float* g2b1 = (const float*)d_in[25];
  const float* g2w2 = (const float*)d_in[26];
  const float* g2b2 = (const float*)d_in[27];
  const float* g2w3 = (const float*)d_in[28];
  const float* g2b3 = (const float*)d_in[29];
  const float* g2w4 = (const float*)d_in[30];
  const float* g2b4 = (const float*)d_in[31];

  constexpr int T16 = 16777216;
  u16* WS  = (u16*)d_ws;
  u16* x0b = WS;
  u16* x1b = WS + (size_t)T16;
  u16* y0b = WS + (size_t)2 * T16;
  u16* y1b = WS + (size_t)3 * T16;
  u16* gyb = WS + (size_t)4 * T16;   // becomes x1g = x1*gy after mlp3c<1>
  u16* gxb = WS + (size_t)5 * T16;   // becomes y1g = y1*gx after mlp3c<1>
  float* fb = (float*)(WS + (size_t)6 * T16);
  float* cs = fb;                    // [0]=wl1 [256]=wl2 [512]=g1w1 [768]=g2w1
  float* ps = fb + 1024;             // [ps0 x0|ps1 y0|ps2 x1|ps3 y1] x16
  u16* wb   = (u16*)(fb + 1024 + 64);

  const u16* wc1b = wb;
  const u16* wc2b = wb + 16384;
  const u16* wl1b = wb + 32768;
  const u16* wl2b = wb + 49152;
  const u16* wl3b = wb + 65536;
  const u16* wl4b = wb + 81920;
  const u16* g1w1b = wb + 98304;
  const u16* g2w1b = wb + 131072;
  const u16* g1w4b = wb + 163840;
  const u16* g2w4b = wb + 196608;
  const u16* g1w2b = wb + 229376;
  const u16* g2w2b = wb + 294912;
  const u16* g1w3b = wb + 360448;
  const u16* g2w3b = wb + 425984;
  const u16* wtb   = wb + 491520;

  float* outx = (float*)d_out;
  float* outy = (float*)d_out + (size_t)T16;

  const dim3 B256(256), B512(512);

  // 1) one-shot weight prep
  prep_k<<<dim3(2437), B256, 0, stream>>>(
      wc1f, wc2f, wl1f, wl2f, wl3f, wl4f, g1w1, g2w1, g1w4, g2w4,
      g1w2, g2w2, g1w3, g2w3, wtf, wb, cs, ps);

  // 2) merged: y0 (ConvT+wc2 fused) + x0 (wc1)  [stats->ps1/ps0]
  gemmYX_k<<<dim3(1536), B256, 0, stream>>>(
      yf, xf, wtb, btf, wc2b, bc2f, wc1b, bc1f, y0b, x0b, ps);

  // 3) dual-branch: y1 = gelu(LN(y0)@wl2+bl2), x1 = gelu(LN(x0)@wl1+bl1)
  gemm4d_k<<<dim3(1024, 2), B256, 0, stream>>>(
      y0b, x0b, wl2b, wl1b, bl2f, bl1f, ps, cs + 256, cs, y1b, x1b);

  // 4) dual-branch gating: mode0 (partial), mode1 (complete + multiply)
  mlp3c_k<0><<<dim3(64, 8, 2), B512, 0, stream>>>(
      y1b, x1b, g2w1b, g1w1b, g2b1, g1b1, ps, cs + 768, cs + 512,
      g2w2b, g1w2b, g2b2, g1b2, g2w4b, g1w4b, g2b4, g1b4, gyb, gxb);
  mlp3c_k<1><<<dim3(64, 8, 2), B512, 0, stream>>>(
      y1b, x1b, g2w1b, g1w1b, g2b1, g1b1, ps, cs + 768, cs + 512,
      g2w3b, g1w3b, g2b3, g1b3, g2w4b, g1w4b, g2b4, g1b4, gyb, gxb);

  // 5) finale: y_out -> outy, x_out -> outx (fp32 NCHW)
  dual5_k<<<dim3(1024), B256, 0, stream>>>(
      gxb, gyb, wl3b, wl4b, bl3f, bl4f, y0b, x0b, outy, outx);
}

// Round 16
// 511.464 us; speedup vs baseline: 1.4038x; 1.4038x over previous
//
#include <hip/hip_runtime.h>
#include <hip/hip_bf16.h>

// ---------------------------------------------------------------------------
// CrossGatingBlock on MI355X (gfx950).  Round 16 = revert to r12 (best: 513.8us).
// r15's 32KB-chunked mlp3c spilled accB (VGPR capped 64 by bounds(512,4)):
// WRITE 65->360MB scratch traffic, 718us.  Locking in the best-known config.
// ---------------------------------------------------------------------------

typedef unsigned short u16;
typedef __bf16 bf16x8 __attribute__((ext_vector_type(8)));
typedef u16    u16x8  __attribute__((ext_vector_type(8)));
typedef u16    u16x4  __attribute__((ext_vector_type(4)));
typedef float  f32x4  __attribute__((ext_vector_type(4)));

__device__ __forceinline__ float bf2f(u16 u) {
  union { float f; unsigned int i; } v; v.i = ((unsigned int)u) << 16; return v.f;
}
__device__ __forceinline__ u16 f2bf(float f) {   // RNE
  union { float f; unsigned int i; } v; v.f = f;
  unsigned int x = v.i;
  return (u16)((x + 0x7fffu + ((x >> 16) & 1u)) >> 16);
}
__device__ __forceinline__ f32x4 mfma16(u16x8 a, u16x8 b, f32x4 c) {
  return __builtin_amdgcn_mfma_f32_16x16x32_bf16(
      __builtin_bit_cast(bf16x8, a), __builtin_bit_cast(bf16x8, b), c, 0, 0, 0);
}
// fast gelu: v * sigmoid(1.5957691*v*(1+0.044715*v^2)), sigmoid via 2^z.
__device__ __forceinline__ float gelu_erf(float v) {
  const float z = v * (-2.3022586f - 0.10294276f * v * v);
  return __fdividef(v, 1.f + exp2f(z));
}

// ---------------------------------------------------------------------------
// prep_k: all weight transposes + 4 LN colsums + stats zeroing.
// ---------------------------------------------------------------------------
__global__ __launch_bounds__(256) void prep_k(
    const float* __restrict__ wc1f, const float* __restrict__ wc2f,
    const float* __restrict__ wl1f, const float* __restrict__ wl2f,
    const float* __restrict__ wl3f, const float* __restrict__ wl4f,
    const float* __restrict__ g1w1, const float* __restrict__ g2w1,
    const float* __restrict__ g1w4, const float* __restrict__ g2w4,
    const float* __restrict__ g1w2, const float* __restrict__ g2w2,
    const float* __restrict__ g1w3, const float* __restrict__ g2w3,
    const float* __restrict__ wtf,
    u16* __restrict__ wb, float* __restrict__ cs, float* __restrict__ ps) {
  const int b = blockIdx.x, t = threadIdx.x;
  if (b < 384) {                       // 6x [128][128]
    const float* src = b < 64 ? wc1f : b < 128 ? wc2f : b < 192 ? wl1f
                     : b < 256 ? wl2f : b < 320 ? wl3f : wl4f;
    const int w = b >> 6;
    const int i = ((b & 63) << 8) + t;           // < 16384
    const int d = i >> 7, c = i & 127;
    wb[w * 16384 + i] = f2bf(src[c * 128 + d]);
  } else if (b < 640) {                // g1w1/g2w1 [128][256] -> [256][128]
    const float* src = b < 512 ? g1w1 : g2w1;
    const int base = b < 512 ? 98304 : 131072;
    const int i = (((b - (b < 512 ? 384 : 512)) << 8) + t);  // < 32768
    const int d = i >> 7, c = i & 127;
    wb[base + i] = f2bf(src[c * 256 + d]);
  } else if (b < 896) {                // g1w4/g2w4 [256][128] -> [128][256]
    const float* src = b < 768 ? g1w4 : g2w4;
    const int base = b < 768 ? 163840 : 196608;
    const int i = (((b - (b < 768 ? 640 : 768)) << 8) + t);  // < 32768
    const int d = i >> 8, c = i & 255;
    wb[base + i] = f2bf(src[c * 128 + d]);
  } else if (b < 1920) {               // 4x [256][256] transpose
    const int w = (b - 896) >> 8;                 // 0..3
    const float* src = w == 0 ? g1w2 : w == 1 ? g2w2 : w == 2 ? g1w3 : g2w3;
    const int base = 229376 + w * 65536;
    const int i = (((b - 896) & 255) << 8) + t;   // < 65536
    const int d = i >> 8, g = i & 255;
    wb[base + i] = f2bf(src[g * 256 + d]);
  } else if (b < 2432) {               // wtb[kl*128+o][c] from wt(c,o,kh,kw)
    const int i = ((b - 1920) << 8) + t;          // < 131072
    const int c = i & 255, r = i >> 8, o = r & 127, kl = r >> 7;
    wb[491520 + i] = f2bf(wtf[(c * 128 + o) * 4 + kl]);
  } else if (b < 2436) {               // colsums (bf16-rounded)
    const int w = b - 2432;
    const float* src = w == 0 ? wl1f : w == 1 ? wl2f : w == 2 ? g1w1 : g2w1;
    const int cout = w < 2 ? 128 : 256;
    if (t < cout) {
      float s = 0.f;
      for (int c = 0; c < 128; ++c) s += bf2f(f2bf(src[c * cout + t]));
      cs[w * 256 + t] = s;
    }
  } else {                             // zero stats slots
    if (t < 64) ps[t] = 0.f;
  }
}

// ---------------------------------------------------------------------------
// gemmYX_k: MERGED first-stage kernel.
// blockIdx.x < 512: y0 = relu(relu(ConvT(y)+bt)@wc2+bc2) [stats->ps+16]
// blockIdx.x >= 512: x0 = relu(x@wc1+bc1)                [stats->ps+0]
// ---------------------------------------------------------------------------
__global__ __launch_bounds__(256, 2) void gemmYX_k(
    const float* __restrict__ Y, const float* __restrict__ X,
    const u16* __restrict__ Wtb, const float* __restrict__ bt,
    const u16* __restrict__ Wc2, const float* __restrict__ bc2,
    const u16* __restrict__ Wc1, const float* __restrict__ bc1,
    u16* __restrict__ oy, u16* __restrict__ ox, float* __restrict__ ps) {
  __shared__ u16 sm[25088];       // Y2: As 16384 + Cs 8704 | X: As 17408
  __shared__ float red[8];
  const int tid = threadIdx.x;
  const int wid = tid >> 6, lane = tid & 63, fr = lane & 15, fg = lane >> 4;

  if (blockIdx.x < 512) {
    // ---------------- Y path (ConvT + conv1x1 fused) ----------------
    u16* As = sm;                 // [64 tok][256 c] swizzled
    u16* Cs = sm + 16384;         // [64 tok][136]
    float* pso = ps + 16;
    const int m0 = blockIdx.x * 64;
    const int ns = m0 >> 12, pb = m0 & 4095;
    const int tokg = (wid & 1) * 32;
    const int chg  = (wid >> 1) * 64;
    const int xorl = (fr & 7) << 4;

#pragma unroll
    for (int it = 0; it < 16; ++it) {
      const int idx = it * 256 + tid;          // < 4096
      const int c = idx & 255, t4 = idx >> 8;  // t4 0..15
      const f32x4 v = *(const f32x4*)(Y + (((size_t)(ns * 256 + c)) << 12) + pb + t4 * 4);
#pragma unroll
      for (int r = 0; r < 4; ++r) {
        const int tok = t4 * 4 + r;
        const int byte = (tok * 512 + c * 2) ^ ((tok & 7) << 4);
        *(u16*)((char*)As + byte) = f2bf(v[r]);
      }
    }
    __syncthreads();

    float s1 = 0.f, s2 = 0.f;
    for (int kl = 0; kl < 4; ++kl) {
      if (kl) __syncthreads();
      f32x4 acc1[2][4] = {};
      {
        const u16* Brow = Wtb + (size_t)(kl * 128 + chg + fr) * 256;
#pragma unroll
        for (int ks = 0; ks < 8; ++ks) {
          const int kb = ks * 32 + fg * 8;
          u16x8 a_[2], b_[4];
#pragma unroll
          for (int i = 0; i < 2; ++i) {
            const int tok = tokg + i * 16 + fr;
            const int byte = (tok * 512 + kb * 2) ^ xorl;
            a_[i] = *(const u16x8*)((const char*)As + byte);
          }
#pragma unroll
          for (int j = 0; j < 4; ++j)
            b_[j] = *(const u16x8*)(Brow + (size_t)j * 16 * 256 + kb);
#pragma unroll
          for (int i = 0; i < 2; ++i)
#pragma unroll
            for (int j = 0; j < 4; ++j) acc1[i][j] = mfma16(b_[j], a_[i], acc1[i][j]);
        }
      }
#pragma unroll
      for (int i = 0; i < 2; ++i) {
        const int tok = tokg + i * 16 + fr;
#pragma unroll
        for (int j = 0; j < 4; ++j) {
          const int o0 = chg + j * 16 + fg * 4;
          const f32x4 bz = *(const f32x4*)(bt + o0);
          u16x4 sv;
#pragma unroll
          for (int r = 0; r < 4; ++r) sv[r] = f2bf(fmaxf(acc1[i][j][r] + bz[r], 0.f));
          *(u16x4*)(Cs + tok * 136 + o0) = sv;
        }
      }
      __syncthreads();
      f32x4 acc2[2][4] = {};
      {
        const u16* Brow = Wc2 + (size_t)(chg + fr) * 128;
#pragma unroll
        for (int ks = 0; ks < 4; ++ks) {
          const int kb = ks * 32 + fg * 8;
          u16x8 a_[2], b_[4];
#pragma unroll
          for (int i = 0; i < 2; ++i)
            a_[i] = *(const u16x8*)(Cs + (tokg + i * 16 + fr) * 136 + kb);
#pragma unroll
          for (int j = 0; j < 4; ++j)
            b_[j] = *(const u16x8*)(Brow + (size_t)j * 16 * 128 + kb);
#pragma unroll
          for (int i = 0; i < 2; ++i)
#pragma unroll
            for (int j = 0; j < 4; ++j) acc2[i][j] = mfma16(b_[j], a_[i], acc2[i][j]);
        }
      }
#pragma unroll
      for (int i = 0; i < 2; ++i) {
        const int ytok = m0 + tokg + i * 16 + fr;
        const int hy = (ytok >> 6) & 63, wy = ytok & 63;
        const int opix = ((ns * 128 + 2 * hy + (kl >> 1)) << 7) + 2 * wy + (kl & 1);
#pragma unroll
        for (int j = 0; j < 4; ++j) {
          const int ch0 = chg + j * 16 + fg * 4;
          const f32x4 bz = *(const f32x4*)(bc2 + ch0);
          u16x4 sv;
#pragma unroll
          for (int r = 0; r < 4; ++r) {
            float v = fmaxf(acc2[i][j][r] + bz[r], 0.f);
            s1 += v; s2 += v * v;
            sv[r] = f2bf(v);
          }
          *(u16x4*)(oy + (size_t)opix * 128 + ch0) = sv;
        }
      }
    }
#pragma unroll
    for (int off = 32; off > 0; off >>= 1) {
      s1 += __shfl_down(s1, off); s2 += __shfl_down(s2, off);
    }
    if (lane == 0) { red[wid] = s1; red[4 + wid] = s2; }
    __syncthreads();
    if (tid == 0)  atomicAdd(&pso[2 * ns],     red[0] + red[1] + red[2] + red[3]);
    if (tid == 64) atomicAdd(&pso[2 * ns + 1], red[4] + red[5] + red[6] + red[7]);
  } else {
    // ---------------- X path (conv1x1 from fp32 NCHW) ----------------
    u16* As = sm;                 // [128 tok][136]
    float* pso = ps;
    const int m0 = (blockIdx.x - 512) * 128;
    const int ns = m0 >> 14, pb = m0 & 16383;
    const int wmt = (wid & 1) * 64, wnc = (wid >> 1) * 64;

#pragma unroll
    for (int it = 0; it < 16; ++it) {
      const int idx = it * 256 + tid;          // < 4096
      const int c = idx & 127, t4 = idx >> 7;  // t4 0..31
      const f32x4 v = *(const f32x4*)(X + (((size_t)(ns * 128 + c)) << 14) + pb + t4 * 4);
#pragma unroll
      for (int r = 0; r < 4; ++r) As[(t4 * 4 + r) * 136 + c] = f2bf(v[r]);
    }
    __syncthreads();

    f32x4 acc[4][4] = {};
    const u16* Brow = Wc1 + (size_t)(wnc + fr) * 128;
    u16x8 a[4][4];
#pragma unroll
    for (int ks = 0; ks < 4; ++ks) {
      const int kb = ks * 32 + fg * 8;
#pragma unroll
      for (int i = 0; i < 4; ++i)
        a[ks][i] = *(const u16x8*)(As + (wmt + i * 16 + fr) * 136 + kb);
    }
#pragma unroll
    for (int ks = 0; ks < 4; ++ks) {
      const int kb = ks * 32 + fg * 8;
      u16x8 b_[4];
#pragma unroll
      for (int j = 0; j < 4; ++j)
        b_[j] = *(const u16x8*)(Brow + (size_t)j * 16 * 128 + kb);
#pragma unroll
      for (int i = 0; i < 4; ++i)
#pragma unroll
        for (int j = 0; j < 4; ++j) acc[i][j] = mfma16(b_[j], a[ks][i], acc[i][j]);
    }

    float s1 = 0.f, s2 = 0.f;
#pragma unroll
    for (int i = 0; i < 4; ++i) {
      const int token = m0 + wmt + i * 16 + fr;
#pragma unroll
      for (int j = 0; j < 4; ++j) {
        const int ch0 = wnc + j * 16 + fg * 4;
        const f32x4 bz = *(const f32x4*)(bc1 + ch0);
        f32x4 v = acc[i][j];
        u16x4 sv;
#pragma unroll
        for (int r = 0; r < 4; ++r) {
          v[r] = fmaxf(v[r] + bz[r], 0.f);
          s1 += v[r]; s2 += v[r] * v[r];
          sv[r] = f2bf(v[r]);
        }
        *(u16x4*)(ox + (size_t)token * 128 + ch0) = sv;
      }
    }
#pragma unroll
    for (int off = 32; off > 0; off >>= 1) {
      s1 += __shfl_down(s1, off); s2 += __shfl_down(s2, off);
    }
    if (lane == 0) { red[wid] = s1; red[4 + wid] = s2; }
    __syncthreads();
    if (tid == 0)  atomicAdd(&pso[2 * ns],     red[0] + red[1] + red[2] + red[3]);
    if (tid == 64) atomicAdd(&pso[2 * ns + 1], red[4] + red[5] + red[6] + red[7]);
  }
}

// ---------------------------------------------------------------------------
// gemm4d_k: DUAL-BRANCH barrier-free CIN=128 GEMM.
// ---------------------------------------------------------------------------
__global__ __launch_bounds__(256, 2) void gemm4d_k(
    const u16* __restrict__ Ay, const u16* __restrict__ Ax,
    const u16* __restrict__ Wty, const u16* __restrict__ Wtx,
    const float* __restrict__ by, const float* __restrict__ bx,
    float* __restrict__ ps,            // [ps0 x0|ps1 y0|ps2 x1|ps3 y1] x16
    const float* __restrict__ csy, const float* __restrict__ csx,
    u16* __restrict__ oy, u16* __restrict__ ox) {
  __shared__ float red[8];
  const int br = blockIdx.y;
  const u16* A1 = br ? Ax : Ay;
  const u16* Wt = br ? Wtx : Wty;
  const float* bias = br ? bx : by;
  const float* pst = ps + (br ? 0 : 16);
  float* pso = ps + (br ? 32 : 48);
  const float* cs = br ? csx : csy;
  u16* out = br ? ox : oy;

  const int tid = threadIdx.x;
  const int m0 = blockIdx.x * 128;
  const int wid = tid >> 6, lane = tid & 63, fr = lane & 15, fg = lane >> 4;
  const int wmt = (wid & 1) * 64, wnc = (wid >> 1) * 64;

  f32x4 acc[4][4] = {};
  const u16* Arow = A1 + (size_t)(m0 + wmt + fr) * 128;
  const u16* Brow = Wt + (size_t)(wnc + fr) * 128;

  u16x8 a[4][4];
#pragma unroll
  for (int ks = 0; ks < 4; ++ks) {
    const int kb = ks * 32 + fg * 8;
#pragma unroll
    for (int i = 0; i < 4; ++i)
      a[ks][i] = *(const u16x8*)(Arow + (size_t)i * 16 * 128 + kb);
  }
#pragma unroll
  for (int ks = 0; ks < 4; ++ks) {
    const int kb = ks * 32 + fg * 8;
    u16x8 b_[4];
#pragma unroll
    for (int j = 0; j < 4; ++j)
      b_[j] = *(const u16x8*)(Brow + (size_t)j * 16 * 128 + kb);
#pragma unroll
    for (int i = 0; i < 4; ++i)
#pragma unroll
      for (int j = 0; j < 4; ++j) acc[i][j] = mfma16(b_[j], a[ks][i], acc[i][j]);
  }

  const int s = m0 >> 14;
  const float inv_n = 1.f / 2097152.f;
  const float mean = pst[2 * s] * inv_n;
  const float var = pst[2 * s + 1] * inv_n - mean * mean;
  const float alpha = rsqrtf(var + 1e-5f);
  const float beta = -mean * alpha;

  float s1 = 0.f, s2 = 0.f;
#pragma unroll
  for (int i = 0; i < 4; ++i) {
    const int token = m0 + wmt + i * 16 + fr;
#pragma unroll
    for (int j = 0; j < 4; ++j) {
      const int ch0 = wnc + j * 16 + fg * 4;
      const f32x4 bz = *(const f32x4*)(bias + ch0);
      const f32x4 csv = *(const f32x4*)(cs + ch0);
      f32x4 v = acc[i][j];
      u16x4 sv;
#pragma unroll
      for (int r = 0; r < 4; ++r) {
        v[r] = v[r] * alpha + beta * csv[r] + bz[r];
        v[r] = gelu_erf(v[r]);
        s1 += v[r]; s2 += v[r] * v[r];
        sv[r] = f2bf(v[r]);
      }
      *(u16x4*)(out + (size_t)token * 128 + ch0) = sv;
    }
  }
#pragma unroll
  for (int off = 32; off > 0; off >>= 1) {
    s1 += __shfl_down(s1, off); s2 += __shfl_down(s2, off);
  }
  if (lane == 0) { red[wid] = s1; red[4 + wid] = s2; }
  __syncthreads();
  if (tid == 0)  atomicAdd(&pso[2 * s],     red[0] + red[1] + red[2] + red[3]);
  if (tid == 64) atomicAdd(&pso[2 * s + 1], red[4] + red[5] + red[6] + red[7]);
}

// ---------------------------------------------------------------------------
// mlp3c_k: DUAL-BRANCH fused gating chain for one channel-half.
// MODE 0 writes g partial (+b4).  MODE 1 adds the partial AND multiplies by
// the OTHER branch's activation -> finished product y1*gx / x1*gy.
// ---------------------------------------------------------------------------
template <int MODE>
__global__ __launch_bounds__(512, 2) void mlp3c_k(
    const u16* __restrict__ a1y, const u16* __restrict__ a1x,
    const u16* __restrict__ w1y, const u16* __restrict__ w1x,
    const float* __restrict__ b1y, const float* __restrict__ b1x,
    const float* __restrict__ ps,
    const float* __restrict__ csy, const float* __restrict__ csx,
    const u16* __restrict__ w2y, const u16* __restrict__ w2x,
    const float* __restrict__ b2y, const float* __restrict__ b2x,
    const u16* __restrict__ w4y, const u16* __restrict__ w4x,
    const float* __restrict__ b4y, const float* __restrict__ b4x,
    u16* __restrict__ goy, u16* __restrict__ gox) {
  __shared__ u16 Ts[34816];     // A/B: [c 128][g 256] (64KB); C: [d 256][136]
  const int br = blockIdx.z;
  const u16* y1 = br ? a1x : a1y;
  const u16* mulp = br ? a1y : a1x;          // other branch's activation
  const u16* w1b = br ? w1x : w1y;
  const float* b1 = br ? b1x : b1y;
  const float* pst = ps + (br ? 32 : 48);
  const float* csb = br ? csx : csy;
  const u16* w2b = br ? w2x : w2y;
  const float* b2 = br ? b2x : b2y;
  const u16* w4b = br ? w4x : w4y;
  const float* b4 = br ? b4x : b4y;
  u16* gout = br ? gox : goy;

  const int q2 = blockIdx.x, ns = blockIdx.y;
  const int tid = threadIdx.x;
  constexpr int coff = MODE ? 128 : 0;
  const int wid = tid >> 6, lane = tid & 63, fr = lane & 15, fg = lane >> 4;
  const int xorl = (fr & 7) << 4;

  int pbase, prow, pcol;
  if constexpr (MODE == 0) {    // q=(gh*16+gw), fixed p2=(ph*8+pw)
    pbase = ns * 16384 + (q2 >> 3) * 128 + (q2 & 7);
    prow = 1024; pcol = 8;
  } else {                      // block cell fixed, q=(ph*16+pw)
    pbase = ns * 16384 + (q2 >> 3) * 2048 + (q2 & 7) * 16;
    prow = 128; pcol = 1;
  }
  auto pix = [&](int q) { return pbase + (q >> 4) * prow + (q & 15) * pcol; };

  // ---------------- stage A: t -> Ts[c][g] ----------------
  {
    const int wgt = (wid >> 1) * 64;     // g: 4 groups
    const int wc  = (wid & 1) * 64;      // c: 2 groups
    const float inv_n = 1.f / 2097152.f;
    const float mean = pst[2 * ns] * inv_n;
    const float var = pst[2 * ns + 1] * inv_n - mean * mean;
    const float alpha = rsqrtf(var + 1e-5f);
    const float beta = -mean * alpha;

    f32x4 acc[4][4] = {};
    const u16* ar[4];
#pragma unroll
    for (int i = 0; i < 4; ++i)
      ar[i] = y1 + (size_t)pix(wgt + i * 16 + fr) * 128;
    const u16* br_ = w1b + (size_t)(coff + wc + fr) * 128;

    u16x8 a[4][4];
#pragma unroll
    for (int ks = 0; ks < 4; ++ks) {
      const int kb = ks * 32 + fg * 8;
#pragma unroll
      for (int i = 0; i < 4; ++i) a[ks][i] = *(const u16x8*)(ar[i] + kb);
    }
#pragma unroll
    for (int ks = 0; ks < 4; ++ks) {
      const int kb = ks * 32 + fg * 8;
      u16x8 b_[4];
#pragma unroll
      for (int j = 0; j < 4; ++j)
        b_[j] = *(const u16x8*)(br_ + (size_t)j * 16 * 128 + kb);
#pragma unroll
      for (int i = 0; i < 4; ++i)
#pragma unroll
        for (int j = 0; j < 4; ++j) acc[i][j] = mfma16(a[ks][i], b_[j], acc[i][j]);
    }
#pragma unroll
    for (int j = 0; j < 4; ++j) {
      const int c = wc + j * 16 + fr;
      const float cv = csb[coff + c];
      const float bz = b1[coff + c];
#pragma unroll
      for (int i = 0; i < 4; ++i) {
        const int g0 = wgt + i * 16 + fg * 4;
        u16x4 sv;
#pragma unroll
        for (int r = 0; r < 4; ++r)
          sv[r] = f2bf(gelu_erf(acc[i][j][r] * alpha + beta * cv + bz));
        const int byte = (c * 512 + g0 * 2) ^ xorl;
        *(u16x4*)((char*)Ts + byte) = sv;
      }
    }
  }
  __syncthreads();

  // ---------------- stage B: m[d][c] in regs ----------------
  f32x4 accB[4][4];             // [i: c-sub][j: d-sub]
  const int wcs = (wid >> 2) * 64;     // c: 2 groups
  const int wds = (wid & 3) * 64;      // d: 4 groups
  {
#pragma unroll
    for (int i = 0; i < 4; ++i)
#pragma unroll
      for (int j = 0; j < 4; ++j) accB[i][j] = f32x4{0.f, 0.f, 0.f, 0.f};
    const u16* br_ = w2b + (size_t)(wds + fr) * 256;
#pragma unroll
    for (int h = 0; h < 2; ++h) {
      u16x8 a[4][4];
#pragma unroll
      for (int ks = 0; ks < 4; ++ks) {
        const int kb = (h * 4 + ks) * 32 + fg * 8;
#pragma unroll
        for (int i = 0; i < 4; ++i) {
          const int c = wcs + i * 16 + fr;
          const int byte = (c * 512 + kb * 2) ^ xorl;
          a[ks][i] = *(const u16x8*)((const char*)Ts + byte);
        }
      }
#pragma unroll
      for (int ks = 0; ks < 4; ++ks) {
        const int kb = (h * 4 + ks) * 32 + fg * 8;
        u16x8 b_[4];
#pragma unroll
        for (int j = 0; j < 4; ++j)
          b_[j] = *(const u16x8*)(br_ + (size_t)j * 16 * 256 + kb);
#pragma unroll
        for (int i = 0; i < 4; ++i)
#pragma unroll
          for (int j = 0; j < 4; ++j) accB[i][j] = mfma16(a[ks][i], b_[j], accB[i][j]);
      }
    }
  }
  __syncthreads();              // all Ts reads done before re-use as Ts2

#pragma unroll
  for (int j = 0; j < 4; ++j) {
    const int d = wds + j * 16 + fr;
    const float bz = b2[d];
#pragma unroll
    for (int i = 0; i < 4; ++i) {
      const int c0 = wcs + i * 16 + fg * 4;
      u16x4 sv;
#pragma unroll
      for (int r = 0; r < 4; ++r) sv[r] = f2bf(accB[i][j][r] + bz);
      *(u16x4*)(Ts + d * 136 + c0) = sv;
    }
  }
  __syncthreads();

  // ---------------- stage C: gpart = Ts2 @ w4half ----------------
  {
    const int wp = (wid >> 1) * 64;    // pixel-d: 4 groups
    const int wo = (wid & 1) * 64;     // o: 2 groups
    f32x4 accC[4][4] = {};             // [i: pix][j: o]
    const u16* br_ = w4b + (size_t)(wo + fr) * 256 + coff;
#pragma unroll
    for (int ks = 0; ks < 4; ++ks) {
      const int kb = ks * 32 + fg * 8;
      u16x8 a_[4], b_[4];
#pragma unroll
      for (int i = 0; i < 4; ++i)
        a_[i] = *(const u16x8*)(Ts + (wp + i * 16 + fr) * 136 + kb);
#pragma unroll
      for (int j = 0; j < 4; ++j)
        b_[j] = *(const u16x8*)(br_ + (size_t)j * 16 * 256 + kb);
#pragma unroll
      for (int i = 0; i < 4; ++i)
#pragma unroll
        for (int j = 0; j < 4; ++j) accC[i][j] = mfma16(b_[j], a_[i], accC[i][j]);
    }
#pragma unroll
    for (int i = 0; i < 4; ++i) {
      const size_t pg = (size_t)pix(wp + i * 16 + fr) * 128;
#pragma unroll
      for (int j = 0; j < 4; ++j) {
        const int o0 = wo + j * 16 + fg * 4;
        f32x4 v = accC[i][j];
        u16x4 sv;
        if constexpr (MODE == 0) {
          const f32x4 bz = *(const f32x4*)(b4 + o0);
#pragma unroll
          for (int r = 0; r < 4; ++r) sv[r] = f2bf(v[r] + bz[r]);
        } else {
          const u16x4 pv = *(const u16x4*)(gout + pg + o0);
          const u16x4 mv = *(const u16x4*)(mulp + pg + o0);
#pragma unroll
          for (int r = 0; r < 4; ++r)
            sv[r] = f2bf((v[r] + bf2f(pv[r])) * bf2f(mv[r]));
        }
        *(u16x4*)(gout + pg + o0) = sv;
      }
    }
  }
}

// ---------------------------------------------------------------------------
// dual5_k: LDS-free, barrier-free finale.
// ---------------------------------------------------------------------------
__global__ __launch_bounds__(256, 2) void dual5_k(
    const u16* __restrict__ y1g, const u16* __restrict__ x1g,
    const u16* __restrict__ w3b, const u16* __restrict__ w4b,
    const float* __restrict__ b3, const float* __restrict__ b4,
    const u16* __restrict__ y0, const u16* __restrict__ x0,
    float* __restrict__ outy, float* __restrict__ outx) {
  const int tid = threadIdx.x;
  const int m0 = blockIdx.x * 128;
  const int wid = tid >> 6, lane = tid & 63, fr = lane & 15, fg = lane >> 4;
  const int wmt = (wid & 1) * 64, wnc = (wid >> 1) * 64;

  f32x4 acc[4][4] = {};
  u16x4 y9[4][4];

  // ---- pass 1: acc = y1g @ w3
  {
    const u16* Arow = y1g + (size_t)(m0 + wmt + fr) * 128;
    const u16* Brow = w3b + (size_t)(wnc + fr) * 128;
    u16x8 a[4][4];
#pragma unroll
    for (int ks = 0; ks < 4; ++ks) {
      const int kb = ks * 32 + fg * 8;
#pragma unroll
      for (int i = 0; i < 4; ++i)
        a[ks][i] = *(const u16x8*)(Arow + (size_t)i * 16 * 128 + kb);
    }
#pragma unroll
    for (int ks = 0; ks < 4; ++ks) {
      const int kb = ks * 32 + fg * 8;
      u16x8 b_[4];
#pragma unroll
      for (int j = 0; j < 4; ++j) b_[j] = *(const u16x8*)(Brow + (size_t)j * 16 * 128 + kb);
#pragma unroll
      for (int i = 0; i < 4; ++i)
#pragma unroll
        for (int j = 0; j < 4; ++j) acc[i][j] = mfma16(b_[j], a[ks][i], acc[i][j]);
    }
  }
  // epilogue 1
  {
    u16x4 scv[4][4];
#pragma unroll
    for (int i = 0; i < 4; ++i) {
      const int token = m0 + wmt + i * 16 + fr;
#pragma unroll
      for (int j = 0; j < 4; ++j)
        scv[i][j] = *(const u16x4*)(y0 + (size_t)token * 128 + wnc + j * 16 + fg * 4);
    }
#pragma unroll
    for (int i = 0; i < 4; ++i) {
      const int token = m0 + wmt + i * 16 + fr;
      const int ns = token >> 14, p = token & 16383;
#pragma unroll
      for (int j = 0; j < 4; ++j) {
        const int ch0 = wnc + j * 16 + fg * 4;
        const f32x4 bz = *(const f32x4*)(b3 + ch0);
        f32x4 v = acc[i][j];
#pragma unroll
        for (int r = 0; r < 4; ++r) {
          v[r] += bz[r] + bf2f(scv[i][j][r]);
          outy[((size_t)(ns * 128 + ch0 + r) << 14) + p] = v[r];
          y9[i][j][r] = f2bf(v[r]);
        }
        acc[i][j] = f32x4{0.f, 0.f, 0.f, 0.f};
      }
    }
  }
  // ---- pass 2: acc = x1g @ w4
  {
    const u16* Arow = x1g + (size_t)(m0 + wmt + fr) * 128;
    const u16* Brow = w4b + (size_t)(wnc + fr) * 128;
    u16x8 a[4][4];
#pragma unroll
    for (int ks = 0; ks < 4; ++ks) {
      const int kb = ks * 32 + fg * 8;
#pragma unroll
      for (int i = 0; i < 4; ++i)
        a[ks][i] = *(const u16x8*)(Arow + (size_t)i * 16 * 128 + kb);
    }
#pragma unroll
    for (int ks = 0; ks < 4; ++ks) {
      const int kb = ks * 32 + fg * 8;
      u16x8 b_[4];
#pragma unroll
      for (int j = 0; j < 4; ++j) b_[j] = *(const u16x8*)(Brow + (size_t)j * 16 * 128 + kb);
#pragma unroll
      for (int i = 0; i < 4; ++i)
#pragma unroll
        for (int j = 0; j < 4; ++j) acc[i][j] = mfma16(b_[j], a[ks][i], acc[i][j]);
    }
  }
  // epilogue 2
  {
    u16x4 scv[4][4];
#pragma unroll
    for (int i = 0; i < 4; ++i) {
      const int token = m0 + wmt + i * 16 + fr;
#pragma unroll
      for (int j = 0; j < 4; ++j)
        scv[i][j] = *(const u16x4*)(x0 + (size_t)token * 128 + wnc + j * 16 + fg * 4);
    }
#pragma unroll
    for (int i = 0; i < 4; ++i) {
      const int token = m0 + wmt + i * 16 + fr;
      const int ns = token >> 14, p = token & 16383;
#pragma unroll
      for (int j = 0; j < 4; ++j) {
        const int ch0 = wnc + j * 16 + fg * 4;
        const f32x4 bz = *(const f32x4*)(b4 + ch0);
        f32x4 v = acc[i][j];
#pragma unroll
        for (int r = 0; r < 4; ++r) {
          v[r] += bz[r] + bf2f(y9[i][j][r]) + bf2f(scv[i][j][r]);
          outx[((size_t)(ns * 128 + ch0 + r) << 14) + p] = v[r];
        }
      }
    }
  }
}

// ---------------------------------------------------------------------------
extern "C" void kernel_launch(void* const* d_in, const int* in_sizes, int n_in,
                              void* d_out, int out_size, void* d_ws, size_t ws_size,
                              hipStream_t stream) {
  (void)in_sizes; (void)n_in; (void)out_size; (void)ws_size;
  const float* xf   = (const float*)d_in[0];
  const float* yf   = (const float*)d_in[1];
  const float* wtf  = (const float*)d_in[2];
  const float* btf  = (const float*)d_in[3];
  const float* wc1f = (const float*)d_in[4];
  const float* bc1f = (const float*)d_in[5];
  const float* wc2f = (const float*)d_in[6];
  const float* bc2f = (const float*)d_in[7];
  const float* wl1f = (const float*)d_in[8];
  const float* bl1f = (const float*)d_in[9];
  const float* wl2f = (const float*)d_in[10];
  const float* bl2f = (const float*)d_in[11];
  const float* wl3f = (const float*)d_in[12];
  const float* bl3f = (const float*)d_in[13];
  const float* wl4f = (const float*)d_in[14];
  const float* bl4f = (const float*)d_in[15];
  const float* g1w1 = (const float*)d_in[16];
  const float* g1b1 = (const float*)d_in[17];
  const float* g1w2 = (const float*)d_in[18];
  const float* g1b2 = (const float*)d_in[19];
  const float* g1w3 = (const float*)d_in[20];
  const float* g1b3 = (const float*)d_in[21];
  const float* g1w4 = (const float*)d_in[22];
  const float* g1b4 = (const float*)d_in[23];
  const float* g2w1 = (const float*)d_in[24];
  const float* g2b1 = (const float*)d_in[25];
  const float* g2w2 = (const float*)d_in[26];
  const float* g2b2 = (const float*)d_in[27];
  const float* g2w3 = (const float*)d_in[28];
  const float* g2b3 = (const float*)d_in[29];
  const float* g2w4 = (const float*)d_in[30];
  const float* g2b4 = (const float*)d_in[31];

  constexpr int T16 = 16777216;
  u16* WS  = (u16*)d_ws;
  u16* x0b = WS;
  u16* x1b = WS + (size_t)T16;
  u16* y0b = WS + (size_t)2 * T16;
  u16* y1b = WS + (size_t)3 * T16;
  u16* gyb = WS + (size_t)4 * T16;   // becomes x1g = x1*gy after mlp3c<1>
  u16* gxb = WS + (size_t)5 * T16;   // becomes y1g = y1*gx after mlp3c<1>
  float* fb = (float*)(WS + (size_t)6 * T16);
  float* cs = fb;                    // [0]=wl1 [256]=wl2 [512]=g1w1 [768]=g2w1
  float* ps = fb + 1024;             // [ps0 x0|ps1 y0|ps2 x1|ps3 y1] x16
  u16* wb   = (u16*)(fb + 1024 + 64);

  const u16* wc1b = wb;
  const u16* wc2b = wb + 16384;
  const u16* wl1b = wb + 32768;
  const u16* wl2b = wb + 49152;
  const u16* wl3b = wb + 65536;
  const u16* wl4b = wb + 81920;
  const u16* g1w1b = wb + 98304;
  const u16* g2w1b = wb + 131072;
  const u16* g1w4b = wb + 163840;
  const u16* g2w4b = wb + 196608;
  const u16* g1w2b = wb + 229376;
  const u16* g2w2b = wb + 294912;
  const u16* g1w3b = wb + 360448;
  const u16* g2w3b = wb + 425984;
  const u16* wtb   = wb + 491520;

  float* outx = (float*)d_out;
  float* outy = (float*)d_out + (size_t)T16;

  const dim3 B256(256), B512(512);

  // 1) one-shot weight prep
  prep_k<<<dim3(2437), B256, 0, stream>>>(
      wc1f, wc2f, wl1f, wl2f, wl3f, wl4f, g1w1, g2w1, g1w4, g2w4,
      g1w2, g2w2, g1w3, g2w3, wtf, wb, cs, ps);

  // 2) merged: y0 (ConvT+wc2 fused) + x0 (wc1)  [stats->ps1/ps0]
  gemmYX_k<<<dim3(1536), B256, 0, stream>>>(
      yf, xf, wtb, btf, wc2b, bc2f, wc1b, bc1f, y0b, x0b, ps);

  // 3) dual-branch: y1 = gelu(LN(y0)@wl2+bl2), x1 = gelu(LN(x0)@wl1+bl1)
  gemm4d_k<<<dim3(1024, 2), B256, 0, stream>>>(
      y0b, x0b, wl2b, wl1b, bl2f, bl1f, ps, cs + 256, cs, y1b, x1b);

  // 4) dual-branch gating: mode0 (partial), mode1 (complete + multiply)
  mlp3c_k<0><<<dim3(64, 8, 2), B512, 0, stream>>>(
      y1b, x1b, g2w1b, g1w1b, g2b1, g1b1, ps, cs + 768, cs + 512,
      g2w2b, g1w2b, g2b2, g1b2, g2w4b, g1w4b, g2b4, g1b4, gyb, gxb);
  mlp3c_k<1><<<dim3(64, 8, 2), B512, 0, stream>>>(
      y1b, x1b, g2w1b, g1w1b, g2b1, g1b1, ps, cs + 768, cs + 512,
      g2w3b, g1w3b, g2b3, g1b3, g2w4b, g1w4b, g2b4, g1b4, gyb, gxb);

  // 5) finale: y_out -> outy, x_out -> outx (fp32 NCHW)
  dual5_k<<<dim3(1024), B256, 0, stream>>>(
      gxb, gyb, wl3b, wl4b, bl3f, bl4f, y0b, x0b, outy, outx);
}